// Round 2
// baseline (570.025 us; speedup 1.0000x reference)
//
#include <hip/hip_runtime.h>
#include <hip/hip_bf16.h>

#define S 9216      // 96*96 spatial positions
#define C 256       // channels
#define NT 72       // 9216 / 128 tiles per dim

typedef __bf16 bf16x8 __attribute__((ext_vector_type(8)));
typedef float f32x4 __attribute__((ext_vector_type(4)));

#define GLOAD_LDS16(g, l) __builtin_amdgcn_global_load_lds( \
    (const __attribute__((address_space(1))) void*)(g),     \
    (__attribute__((address_space(3))) void*)(l), 16, 0, 0)

// ---------------- mean of gt over spatial, per channel ----------------
__global__ __launch_bounds__(256) void k_mean(const float* __restrict__ gt,
                                              float* __restrict__ meanT) {
    const int c = blockIdx.x;
    const float* p = gt + (size_t)c * S;
    float s = 0.f;
    for (int i = threadIdx.x; i < S; i += 256) s += p[i];
    for (int m = 1; m < 64; m <<= 1) s += __shfl_xor(s, m, 64);
    __shared__ float red[4];
    if ((threadIdx.x & 63) == 0) red[threadIdx.x >> 6] = s;
    __syncthreads();
    if (threadIdx.x == 0)
        meanT[c] = (red[0] + red[1] + red[2] + red[3]) * (1.0f / S);
}

// ------- center by mean_t, L2-normalize over C, transpose to [S][C] bf16 -------
// 4 lanes per spatial position, 64 channels each.
__global__ __launch_bounds__(256) void k_norm(const float* __restrict__ img,
                                              const float* __restrict__ gt,
                                              const float* __restrict__ meanT,
                                              __hip_bfloat16* __restrict__ A,
                                              __hip_bfloat16* __restrict__ B) {
    __shared__ float sm[C];
    if (threadIdx.x < C) sm[threadIdx.x] = meanT[threadIdx.x];
    __syncthreads();
    const int gtid = blockIdx.x * 256 + threadIdx.x;
    const int s    = gtid >> 2;          // spatial position
    const int part = gtid & 3;           // channel quarter
    const int c0   = part * 64;
    float si = 0.f, st = 0.f;
    for (int k = 0; k < 64; ++k) {
        const int c = c0 + k;
        const float m  = sm[c];
        const float di = img[(size_t)c * S + s] - m;
        const float dt = gt [(size_t)c * S + s] - m;
        si += di * di;
        st += dt * dt;
    }
    // combine the 4 lanes covering this position (xor 1,2 stays in the group)
    si += __shfl_xor(si, 1, 64); si += __shfl_xor(si, 2, 64);
    st += __shfl_xor(st, 1, 64); st += __shfl_xor(st, 2, 64);
    const float ri = 1.0f / fmaxf(sqrtf(si), 1e-12f);
    const float rt = 1.0f / fmaxf(sqrtf(st), 1e-12f);
    for (int k = 0; k < 64; ++k) {
        const int c = c0 + k;
        const float m = sm[c];
        A[(size_t)s * C + c] = __float2bfloat16((img[(size_t)c * S + s] - m) * ri);
        B[(size_t)s * C + c] = __float2bfloat16((gt [(size_t)c * S + s] - m) * rt);
    }
}

// ---------------- init reduction buffers ----------------
__global__ __launch_bounds__(256) void k_init(float* __restrict__ rowmin,
                                              float* __restrict__ rowsum,
                                              float* __restrict__ colmax) {
    const int i = blockIdx.x * 256 + threadIdx.x;
    if (i < S) {
        rowmin[i] = __uint_as_float(0x7f800000u);  // +inf
        rowsum[i] = 0.f;
        colmax[i] = 0.f;
    }
}

// ---------------- fused GEMM passes ----------------
// dot[r,s] = sum_c A[r,c]*B[s,c]; raw = max((1-dot)/2, 0)
// PASS 1: rowmin[r] = min_s raw            (atomicMin on uint bits, raw>=0)
// PASS 2: rowsum[r] = sum_s exp(2(1-raw/(rowmin+eps)))
// PASS 3: colmax[s] = max_r w/rowsum[r]    (atomicMax on uint bits)
//
// Full-K staging: LDS [2 halves][128 rows][128 k-elems] per operand (64KB each,
// 128KB total -> 1 block/CU). Two raw s_barriers, counted vmcnt (T4): compute
// half 0 while half 1 loads are still in flight. XOR-swizzled chunks
// (chunk ^ (row&7)) applied on BOTH the pre-swizzled global source and the
// LDS read (rule #21) -> conflict-free ds_read_b128.
template<int PASS>
__global__ __launch_bounds__(256, 1) void k_gemm(const __hip_bfloat16* __restrict__ A,
                                                 const __hip_bfloat16* __restrict__ B,
                                                 float* __restrict__ rowmin,
                                                 float* __restrict__ rowsum,
                                                 float* __restrict__ colmax) {
    __shared__ alignas(16) __hip_bfloat16 As[2 * 128 * 128];   // 64 KB
    __shared__ alignas(16) __hip_bfloat16 Bs[2 * 128 * 128];   // 64 KB
    const int tid  = threadIdx.x;
    const int lane = tid & 63;
    const int wid  = tid >> 6;
    const int wr   = wid >> 1;      // wave row (0..1), 64 rows each
    const int wc   = wid & 1;       // wave col (0..1), 64 cols each
    const int rowBase = blockIdx.y * 128;
    const int colBase = blockIdx.x * 128;

    const int frow = lane & 15;     // A-row / B-col within 16x16 frag
    const int kgrp = lane >> 4;     // k-group: elements kgrp*8 .. +8

    const int srow   = lane >> 4;   // staging: row within 4-row chunk
    const int schunk = lane & 15;   // staging: 16B chunk within 128-elem half-row

    // ---- issue ALL staging loads (16 per half per thread; A+B interleaved)
    #pragma unroll
    for (int h = 0; h < 2; ++h) {
        #pragma unroll
        for (int j = 0; j < 8; ++j) {
            const int r0  = wid * 32 + j * 4;       // wave-uniform base row
            const int row = r0 + srow;
            const int cc  = schunk ^ (row & 7);     // pre-swizzled source chunk
            const size_t gcol = (size_t)h * 128 + cc * 8;
            GLOAD_LDS16(A + (size_t)(rowBase + row) * C + gcol,
                        &As[h * 16384 + r0 * 128]);
            GLOAD_LDS16(B + (size_t)(colBase + row) * C + gcol,
                        &Bs[h * 16384 + r0 * 128]);
        }
    }

    f32x4 acc[4][4] = {};

    #pragma unroll
    for (int h = 0; h < 2; ++h) {
        if (h == 0) asm volatile("s_waitcnt vmcnt(16)" ::: "memory"); // half0 done, half1 in flight
        else        asm volatile("s_waitcnt vmcnt(0)"  ::: "memory");
        __builtin_amdgcn_s_barrier();
        #pragma unroll
        for (int kk = 0; kk < 4; ++kk) {
            const int ch = ((kk * 4 + kgrp) ^ (frow & 7)) * 8;  // swizzled read chunk
            bf16x8 af[4], bfr[4];
            #pragma unroll
            for (int m = 0; m < 4; ++m)
                af[m] = *reinterpret_cast<const bf16x8*>(
                    &As[h * 16384 + (wr * 64 + m * 16 + frow) * 128 + ch]);
            #pragma unroll
            for (int n = 0; n < 4; ++n)
                bfr[n] = *reinterpret_cast<const bf16x8*>(
                    &Bs[h * 16384 + (wc * 64 + n * 16 + frow) * 128 + ch]);
            #pragma unroll
            for (int m = 0; m < 4; ++m)
                #pragma unroll
                for (int n = 0; n < 4; ++n)
                    acc[m][n] = __builtin_amdgcn_mfma_f32_16x16x32_bf16(af[m], bfr[n], acc[m][n], 0, 0, 0);
        }
    }

    // ---- epilogue: C/D mapping: col = lane&15, row = (lane>>4)*4 + q [m89]
    if (PASS == 1) {
        for (int m = 0; m < 4; ++m)
            for (int q = 0; q < 4; ++q) {
                float v = 1e30f;
                for (int n = 0; n < 4; ++n) {
                    const float raw = fmaxf(0.5f * (1.0f - acc[m][n][q]), 0.0f);
                    v = fminf(v, raw);
                }
                v = fminf(v, __shfl_xor(v, 1, 64));
                v = fminf(v, __shfl_xor(v, 2, 64));
                v = fminf(v, __shfl_xor(v, 4, 64));
                v = fminf(v, __shfl_xor(v, 8, 64));
                if (frow == 0) {
                    const int rg = rowBase + wr * 64 + m * 16 + kgrp * 4 + q;
                    atomicMin((unsigned int*)&rowmin[rg], __float_as_uint(v));
                }
            }
    } else if (PASS == 2) {
        for (int m = 0; m < 4; ++m)
            for (int q = 0; q < 4; ++q) {
                const int rg = rowBase + wr * 64 + m * 16 + kgrp * 4 + q;
                const float inv = 1.0f / (rowmin[rg] + 1e-5f);
                float sum = 0.f;
                for (int n = 0; n < 4; ++n) {
                    const float raw = fmaxf(0.5f * (1.0f - acc[m][n][q]), 0.0f);
                    sum += __expf(2.0f * (1.0f - raw * inv));
                }
                sum += __shfl_xor(sum, 1, 64);
                sum += __shfl_xor(sum, 2, 64);
                sum += __shfl_xor(sum, 4, 64);
                sum += __shfl_xor(sum, 8, 64);
                if (frow == 0) atomicAdd(&rowsum[rg], sum);
            }
    } else {
        float cmax[4] = {0.f, 0.f, 0.f, 0.f};
        for (int m = 0; m < 4; ++m)
            for (int q = 0; q < 4; ++q) {
                const int rg = rowBase + wr * 64 + m * 16 + kgrp * 4 + q;
                const float inv = 1.0f / (rowmin[rg] + 1e-5f);
                const float rs  = 1.0f / rowsum[rg];
                for (int n = 0; n < 4; ++n) {
                    const float raw = fmaxf(0.5f * (1.0f - acc[m][n][q]), 0.0f);
                    const float cx  = __expf(2.0f * (1.0f - raw * inv)) * rs;
                    cmax[n] = fmaxf(cmax[n], cx);
                }
            }
        for (int n = 0; n < 4; ++n) {
            float v = cmax[n];
            v = fmaxf(v, __shfl_xor(v, 16, 64));
            v = fmaxf(v, __shfl_xor(v, 32, 64));
            if (kgrp == 0) {
                const int cg = colBase + wc * 64 + n * 16 + frow;
                atomicMax((unsigned int*)&colmax[cg], __float_as_uint(v));
            }
        }
    }
}

// ---------------- final: loss = -log(mean_s colmax[s]) ----------------
__global__ __launch_bounds__(256) void k_final(const float* __restrict__ colmax,
                                               float* __restrict__ out) {
    float s = 0.f;
    for (int i = threadIdx.x; i < S; i += 256) s += colmax[i];
    for (int m = 1; m < 64; m <<= 1) s += __shfl_xor(s, m, 64);
    __shared__ float red[4];
    if ((threadIdx.x & 63) == 0) red[threadIdx.x >> 6] = s;
    __syncthreads();
    if (threadIdx.x == 0)
        out[0] = -logf((red[0] + red[1] + red[2] + red[3]) * (1.0f / S));
}

extern "C" void kernel_launch(void* const* d_in, const int* in_sizes, int n_in,
                              void* d_out, int out_size, void* d_ws, size_t ws_size,
                              hipStream_t stream) {
    const float* img = (const float*)d_in[0];
    const float* gt  = (const float*)d_in[1];

    float* ws     = (float*)d_ws;
    float* meanT  = ws;                  // 256
    float* rowmin = ws + 256;            // 9216
    float* rowsum = rowmin + S;          // 9216
    float* colmax = rowsum + S;          // 9216
    __hip_bfloat16* A = (__hip_bfloat16*)(colmax + S);   // byte off 111616 (16B aligned)
    __hip_bfloat16* B = A + (size_t)S * C;
    float* out = (float*)d_out;

    k_mean<<<C, 256, 0, stream>>>(gt, meanT);
    k_norm<<<(S * 4) / 256, 256, 0, stream>>>(img, gt, meanT, A, B);
    k_init<<<(S + 255) / 256, 256, 0, stream>>>(rowmin, rowsum, colmax);

    dim3 grid(NT, NT);
    k_gemm<1><<<grid, 256, 0, stream>>>(A, B, rowmin, rowsum, colmax);
    k_gemm<2><<<grid, 256, 0, stream>>>(A, B, rowmin, rowsum, colmax);
    k_gemm<3><<<grid, 256, 0, stream>>>(A, B, rowmin, rowsum, colmax);

    k_final<<<1, 256, 0, stream>>>(colmax, out);
}

// Round 3
// 374.482 us; speedup vs baseline: 1.5222x; 1.5222x over previous
//
#include <hip/hip_runtime.h>
#include <hip/hip_bf16.h>

#define S 9216      // 96*96 spatial positions
#define C 256       // channels
#define NCT 4       // column tiles per block
#define NG  (NCT*8) // total kt-steps per block (8 kt of BK=32 per tile)

typedef __bf16 bf16x8 __attribute__((ext_vector_type(8)));
typedef float f32x4 __attribute__((ext_vector_type(4)));

#define GLOAD_LDS16(g, l) __builtin_amdgcn_global_load_lds( \
    (const __attribute__((address_space(1))) void*)(g),     \
    (__attribute__((address_space(3))) void*)(l), 16, 0, 0)

// ---------------- mean of gt over spatial, per channel ----------------
__global__ __launch_bounds__(256) void k_mean(const float* __restrict__ gt,
                                              float* __restrict__ meanT) {
    const int c = blockIdx.x;
    const float* p = gt + (size_t)c * S;
    float s = 0.f;
    for (int i = threadIdx.x; i < S; i += 256) s += p[i];
    for (int m = 1; m < 64; m <<= 1) s += __shfl_xor(s, m, 64);
    __shared__ float red[4];
    if ((threadIdx.x & 63) == 0) red[threadIdx.x >> 6] = s;
    __syncthreads();
    if (threadIdx.x == 0)
        meanT[c] = (red[0] + red[1] + red[2] + red[3]) * (1.0f / S);
}

// ------- center by mean_t, L2-normalize over C, transpose to [S][C] bf16 -------
__global__ __launch_bounds__(256) void k_norm(const float* __restrict__ img,
                                              const float* __restrict__ gt,
                                              const float* __restrict__ meanT,
                                              __hip_bfloat16* __restrict__ A,
                                              __hip_bfloat16* __restrict__ B) {
    __shared__ float sm[C];
    if (threadIdx.x < C) sm[threadIdx.x] = meanT[threadIdx.x];
    __syncthreads();
    const int gtid = blockIdx.x * 256 + threadIdx.x;
    const int s    = gtid >> 2;          // spatial position
    const int part = gtid & 3;           // channel quarter
    const int c0   = part * 64;
    float si = 0.f, st = 0.f;
    for (int k = 0; k < 64; ++k) {
        const int c = c0 + k;
        const float m  = sm[c];
        const float di = img[(size_t)c * S + s] - m;
        const float dt = gt [(size_t)c * S + s] - m;
        si += di * di;
        st += dt * dt;
    }
    si += __shfl_xor(si, 1, 64); si += __shfl_xor(si, 2, 64);
    st += __shfl_xor(st, 1, 64); st += __shfl_xor(st, 2, 64);
    const float ri = 1.0f / fmaxf(sqrtf(si), 1e-12f);
    const float rt = 1.0f / fmaxf(sqrtf(st), 1e-12f);
    for (int k = 0; k < 64; ++k) {
        const int c = c0 + k;
        const float m = sm[c];
        A[(size_t)s * C + c] = __float2bfloat16((img[(size_t)c * S + s] - m) * ri);
        B[(size_t)s * C + c] = __float2bfloat16((gt [(size_t)c * S + s] - m) * rt);
    }
}

// ---------------- init reduction buffers ----------------
__global__ __launch_bounds__(256) void k_init(float* __restrict__ rowmin,
                                              float* __restrict__ rowsum,
                                              float* __restrict__ colmax) {
    const int i = blockIdx.x * 256 + threadIdx.x;
    if (i < S) {
        rowmin[i] = __uint_as_float(0x7f800000u);  // +inf
        rowsum[i] = 0.f;
        colmax[i] = 0.f;
    }
}

// ---------------- fused GEMM passes (A-resident, B streamed) ----------------
// Block owns 128 rows with FULL K=256 of A in LDS (64KB, staged once),
// sweeps NCT=4 column tiles of 128, streaming B via double-buffered 8KB
// stages with counted vmcnt (wait vmcnt(2): current ready, next in flight).
// LDS = 64 + 16 = 80KB -> 2 blocks/CU.
// Swizzles (both-sides, rule 21):
//   A [128][32 x 16B chunks]: phys = logical ^ (row&7)      (spreads 8 rows over 32 banks)
//   B [128][ 4 x 16B chunks]: phys = logical ^ ((row>>1)&3) (with bank bit6 = row&1)
template<int PASS>
__global__ __launch_bounds__(256, 2) void k_gemm(const __hip_bfloat16* __restrict__ A,
                                                 const __hip_bfloat16* __restrict__ B,
                                                 float* __restrict__ rowmin,
                                                 float* __restrict__ rowsum,
                                                 float* __restrict__ colmax) {
    __shared__ alignas(16) __hip_bfloat16 As[128 * 256];      // 64 KB
    __shared__ alignas(16) __hip_bfloat16 Bs[2 * 128 * 32];   // 16 KB
    const int tid  = threadIdx.x;
    const int lane = tid & 63;
    const int wid  = tid >> 6;
    const int wr   = wid >> 1;      // wave row (0..1), 64 rows each
    const int wc   = wid & 1;       // wave col (0..1), 64 cols each
    const int rowBase = blockIdx.y * 128;
    const int colBase0 = blockIdx.x * (NCT * 128);

    const int frow = lane & 15;     // A-row / B-col within 16x16 frag
    const int kgrp = lane >> 4;     // k-group: elements kgrp*8 .. +8

    // ---- prologue: stage A full-K (16 loads/thread), then B for g=0,1
    {
        const int arow_lo = (lane >> 5);        // 0/1
        const int achunk  = lane & 31;
        #pragma unroll
        for (int j = 0; j < 16; ++j) {
            const int row = wid * 32 + j * 2 + arow_lo;
            const int c   = achunk ^ (row & 7);
            GLOAD_LDS16(A + (size_t)(rowBase + row) * C + c * 8,
                        &As[wid * 8192 + j * 512 + lane * 8]);
        }
    }
    const int brow_lo = lane >> 2;              // 0..15
    const int bchunk  = (lane & 3) ^ ((lane >> 3) & 3);
    #pragma unroll
    for (int g = 0; g < 2; ++g) {
        const int cb = colBase0 + (g >> 3) * 128;
        const int kt = g & 7;
        #pragma unroll
        for (int i = 0; i < 2; ++i) {
            const int row = wid * 16 + i * 64 + brow_lo;
            GLOAD_LDS16(B + (size_t)(cb + row) * C + kt * 32 + bchunk * 8,
                        &Bs[(g & 1) * 4096 + wid * 512 + i * 2048 + lane * 8]);
        }
    }

    const int bswz = (kgrp ^ ((frow >> 1) & 3)) * 8;

    for (int t = 0; t < NCT; ++t) {
        f32x4 acc[4][4] = {};
        #pragma unroll
        for (int kt = 0; kt < 8; ++kt) {
            const int g = t * 8 + kt;
            if (g < NG - 1) asm volatile("s_waitcnt vmcnt(2)" ::: "memory");
            else            asm volatile("s_waitcnt vmcnt(0)" ::: "memory");
            __builtin_amdgcn_s_barrier();

            bf16x8 af[4], bfr[4];
            #pragma unroll
            for (int m = 0; m < 4; ++m) {
                const int row = wr * 64 + m * 16 + frow;
                const int p   = (kt * 4 + kgrp) ^ (frow & 7);
                af[m] = *reinterpret_cast<const bf16x8*>(&As[row * 256 + p * 8]);
            }
            const int bbase = (g & 1) * 4096;
            #pragma unroll
            for (int n = 0; n < 4; ++n) {
                const int row = wc * 64 + n * 16 + frow;
                bfr[n] = *reinterpret_cast<const bf16x8*>(&Bs[bbase + row * 32 + bswz]);
            }
            #pragma unroll
            for (int m = 0; m < 4; ++m)
                #pragma unroll
                for (int n = 0; n < 4; ++n)
                    acc[m][n] = __builtin_amdgcn_mfma_f32_16x16x32_bf16(af[m], bfr[n], acc[m][n], 0, 0, 0);

            __builtin_amdgcn_s_barrier();

            if (g + 2 < NG) {
                const int g2 = g + 2;
                const int cb = colBase0 + (g2 >> 3) * 128;
                const int k2 = g2 & 7;
                #pragma unroll
                for (int i = 0; i < 2; ++i) {
                    const int row = wid * 16 + i * 64 + brow_lo;
                    GLOAD_LDS16(B + (size_t)(cb + row) * C + k2 * 32 + bchunk * 8,
                                &Bs[(g2 & 1) * 4096 + wid * 512 + i * 2048 + lane * 8]);
                }
            }
        }

        // ---- epilogue for tile t: C/D mapping col=lane&15, row=(lane>>4)*4+q
        const int colBase = colBase0 + t * 128;
        if (PASS == 1) {
            for (int m = 0; m < 4; ++m)
                for (int q = 0; q < 4; ++q) {
                    float v = 1e30f;
                    for (int n = 0; n < 4; ++n) {
                        const float raw = fmaxf(0.5f * (1.0f - acc[m][n][q]), 0.0f);
                        v = fminf(v, raw);
                    }
                    v = fminf(v, __shfl_xor(v, 1, 64));
                    v = fminf(v, __shfl_xor(v, 2, 64));
                    v = fminf(v, __shfl_xor(v, 4, 64));
                    v = fminf(v, __shfl_xor(v, 8, 64));
                    if (frow == 0) {
                        const int rg = rowBase + wr * 64 + m * 16 + kgrp * 4 + q;
                        atomicMin((unsigned int*)&rowmin[rg], __float_as_uint(v));
                    }
                }
        } else if (PASS == 2) {
            for (int m = 0; m < 4; ++m)
                for (int q = 0; q < 4; ++q) {
                    const int rg = rowBase + wr * 64 + m * 16 + kgrp * 4 + q;
                    const float inv = 1.0f / (rowmin[rg] + 1e-5f);
                    float sum = 0.f;
                    for (int n = 0; n < 4; ++n) {
                        const float raw = fmaxf(0.5f * (1.0f - acc[m][n][q]), 0.0f);
                        sum += __expf(2.0f * (1.0f - raw * inv));
                    }
                    sum += __shfl_xor(sum, 1, 64);
                    sum += __shfl_xor(sum, 2, 64);
                    sum += __shfl_xor(sum, 4, 64);
                    sum += __shfl_xor(sum, 8, 64);
                    if (frow == 0) atomicAdd(&rowsum[rg], sum);
                }
        } else {
            float cmax[4] = {0.f, 0.f, 0.f, 0.f};
            for (int m = 0; m < 4; ++m)
                for (int q = 0; q < 4; ++q) {
                    const int rg = rowBase + wr * 64 + m * 16 + kgrp * 4 + q;
                    const float inv = 1.0f / (rowmin[rg] + 1e-5f);
                    const float rs  = 1.0f / rowsum[rg];
                    for (int n = 0; n < 4; ++n) {
                        const float raw = fmaxf(0.5f * (1.0f - acc[m][n][q]), 0.0f);
                        const float cx  = __expf(2.0f * (1.0f - raw * inv)) * rs;
                        cmax[n] = fmaxf(cmax[n], cx);
                    }
                }
            for (int n = 0; n < 4; ++n) {
                float v = cmax[n];
                v = fmaxf(v, __shfl_xor(v, 16, 64));
                v = fmaxf(v, __shfl_xor(v, 32, 64));
                if (kgrp == 0) {
                    const int cg = colBase + wc * 64 + n * 16 + frow;
                    atomicMax((unsigned int*)&colmax[cg], __float_as_uint(v));
                }
            }
        }
    }
}

// ---------------- final: loss = -log(mean_s colmax[s]) ----------------
__global__ __launch_bounds__(256) void k_final(const float* __restrict__ colmax,
                                               float* __restrict__ out) {
    float s = 0.f;
    for (int i = threadIdx.x; i < S; i += 256) s += colmax[i];
    for (int m = 1; m < 64; m <<= 1) s += __shfl_xor(s, m, 64);
    __shared__ float red[4];
    if ((threadIdx.x & 63) == 0) red[threadIdx.x >> 6] = s;
    __syncthreads();
    if (threadIdx.x == 0)
        out[0] = -logf((red[0] + red[1] + red[2] + red[3]) * (1.0f / S));
}

extern "C" void kernel_launch(void* const* d_in, const int* in_sizes, int n_in,
                              void* d_out, int out_size, void* d_ws, size_t ws_size,
                              hipStream_t stream) {
    const float* img = (const float*)d_in[0];
    const float* gt  = (const float*)d_in[1];

    float* ws     = (float*)d_ws;
    float* meanT  = ws;                  // 256
    float* rowmin = ws + 256;            // 9216
    float* rowsum = rowmin + S;          // 9216
    float* colmax = rowsum + S;          // 9216
    __hip_bfloat16* A = (__hip_bfloat16*)(colmax + S);   // 16B-aligned offset
    __hip_bfloat16* B = A + (size_t)S * C;
    float* out = (float*)d_out;

    k_mean<<<C, 256, 0, stream>>>(gt, meanT);
    k_norm<<<(S * 4) / 256, 256, 0, stream>>>(img, gt, meanT, A, B);
    k_init<<<(S + 255) / 256, 256, 0, stream>>>(rowmin, rowsum, colmax);

    dim3 grid(72 / NCT, 72);   // 18 x 72 = 1296 blocks
    k_gemm<1><<<grid, 256, 0, stream>>>(A, B, rowmin, rowsum, colmax);
    k_gemm<2><<<grid, 256, 0, stream>>>(A, B, rowmin, rowsum, colmax);
    k_gemm<3><<<grid, 256, 0, stream>>>(A, B, rowmin, rowsum, colmax);

    k_final<<<1, 256, 0, stream>>>(colmax, out);
}

// Round 4
// 268.636 us; speedup vs baseline: 2.1219x; 1.3940x over previous
//
#include <hip/hip_runtime.h>
#include <hip/hip_bf16.h>

#define S 9216      // 96*96 spatial positions
#define C 256       // channels
#define NCT 8       // column tiles per block (hybrid GEMM)
#define NG  (NCT*8) // kt-steps per block
#define NCT3 4      // fallback GEMM
#define NG3 (NCT3*8)

typedef __bf16 bf16x8 __attribute__((ext_vector_type(8)));
typedef float f32x4 __attribute__((ext_vector_type(4)));
typedef unsigned short us8 __attribute__((ext_vector_type(8)));
typedef unsigned short us4 __attribute__((ext_vector_type(4)));

#define GLOAD_LDS16(g, l) __builtin_amdgcn_global_load_lds( \
    (const __attribute__((address_space(1))) void*)(g),     \
    (__attribute__((address_space(3))) void*)(l), 16, 0, 0)

__device__ __forceinline__ float bf2f(unsigned short u) {
    return __uint_as_float(((unsigned)u) << 16);
}

// ---------------- mean of gt over spatial, per channel ----------------
__global__ __launch_bounds__(256) void k_mean(const float* __restrict__ gt,
                                              float* __restrict__ meanT) {
    const int c = blockIdx.x;
    const float* p = gt + (size_t)c * S;
    float s = 0.f;
    for (int i = threadIdx.x; i < S; i += 256) s += p[i];
    for (int m = 1; m < 64; m <<= 1) s += __shfl_xor(s, m, 64);
    __shared__ float red[4];
    if ((threadIdx.x & 63) == 0) red[threadIdx.x >> 6] = s;
    __syncthreads();
    if (threadIdx.x == 0)
        meanT[c] = (red[0] + red[1] + red[2] + red[3]) * (1.0f / S);
}

// ------- center by mean_t, L2-normalize over C, transpose to [S][C] bf16 -------
__global__ __launch_bounds__(256) void k_norm(const float* __restrict__ img,
                                              const float* __restrict__ gt,
                                              const float* __restrict__ meanT,
                                              __hip_bfloat16* __restrict__ A,
                                              __hip_bfloat16* __restrict__ B) {
    __shared__ float sm[C];
    if (threadIdx.x < C) sm[threadIdx.x] = meanT[threadIdx.x];
    __syncthreads();
    const int gtid = blockIdx.x * 256 + threadIdx.x;
    const int s    = gtid >> 2;          // spatial position
    const int part = gtid & 3;           // channel quarter
    const int c0   = part * 64;
    float si = 0.f, st = 0.f;
    for (int k = 0; k < 64; ++k) {
        const int c = c0 + k;
        const float m  = sm[c];
        const float di = img[(size_t)c * S + s] - m;
        const float dt = gt [(size_t)c * S + s] - m;
        si += di * di;
        st += dt * dt;
    }
    si += __shfl_xor(si, 1, 64); si += __shfl_xor(si, 2, 64);
    st += __shfl_xor(st, 1, 64); st += __shfl_xor(st, 2, 64);
    const float ri = 1.0f / fmaxf(sqrtf(si), 1e-12f);
    const float rt = 1.0f / fmaxf(sqrtf(st), 1e-12f);
    for (int k = 0; k < 64; ++k) {
        const int c = c0 + k;
        const float m = sm[c];
        A[(size_t)s * C + c] = __float2bfloat16((img[(size_t)c * S + s] - m) * ri);
        B[(size_t)s * C + c] = __float2bfloat16((gt [(size_t)c * S + s] - m) * rt);
    }
}

// ---------------- init reduction buffers ----------------
__global__ __launch_bounds__(256) void k_init(float* __restrict__ rowmin,
                                              float* __restrict__ rowsum,
                                              float* __restrict__ colmax) {
    const int i = blockIdx.x * 256 + threadIdx.x;
    if (i < S) {
        rowmin[i] = __uint_as_float(0x7f800000u);  // +inf
        rowsum[i] = 0.f;
        colmax[i] = 0.f;
    }
}

// =====================================================================
// HYBRID PATH: one GEMM pass storing raw (transposed, bf16) + rowmin,
// then a streaming pass computing rowsum / cx / colmax from stored raw.
// =====================================================================

// A-resident GEMM (r3 structure, NCT=8), epilogue: store raw to Q[s][r]
// as bf16x4 (4 consecutive r per lane = 8B stores) + rowmin atomicMin.
__global__ __launch_bounds__(256, 2) void k_gemm_store(const __hip_bfloat16* __restrict__ A,
                                                       const __hip_bfloat16* __restrict__ B,
                                                       float* __restrict__ rowmin,
                                                       __hip_bfloat16* __restrict__ Q) {
    __shared__ alignas(16) __hip_bfloat16 As[128 * 256];      // 64 KB
    __shared__ alignas(16) __hip_bfloat16 Bs[2 * 128 * 32];   // 16 KB
    const int tid  = threadIdx.x;
    const int lane = tid & 63;
    const int wid  = tid >> 6;
    const int wr   = wid >> 1;
    const int wc   = wid & 1;
    // XCD-aware bijective swizzle: 648 = 8 * 81
    const int orig = blockIdx.x;
    const int wg   = (orig & 7) * 81 + (orig >> 3);
    const int rowBase  = (wg / 9) * 128;
    const int colBase0 = (wg % 9) * (NCT * 128);

    const int frow = lane & 15;
    const int kgrp = lane >> 4;

    // ---- prologue: stage A full-K (16 loads/thread), then B for g=0,1
    {
        const int arow_lo = (lane >> 5);
        const int achunk  = lane & 31;
        #pragma unroll
        for (int j = 0; j < 16; ++j) {
            const int row = wid * 32 + j * 2 + arow_lo;
            const int c   = achunk ^ (row & 7);
            GLOAD_LDS16(A + (size_t)(rowBase + row) * C + c * 8,
                        &As[wid * 8192 + j * 512 + lane * 8]);
        }
    }
    const int brow_lo = lane >> 2;
    const int bchunk  = (lane & 3) ^ ((lane >> 3) & 3);
    #pragma unroll
    for (int g = 0; g < 2; ++g) {
        const int cb = colBase0 + (g >> 3) * 128;
        const int kt = g & 7;
        #pragma unroll
        for (int i = 0; i < 2; ++i) {
            const int row = wid * 16 + i * 64 + brow_lo;
            GLOAD_LDS16(B + (size_t)(cb + row) * C + kt * 32 + bchunk * 8,
                        &Bs[(g & 1) * 4096 + wid * 512 + i * 2048 + lane * 8]);
        }
    }

    const int bswz = (kgrp ^ ((frow >> 1) & 3)) * 8;

    for (int t = 0; t < NCT; ++t) {
        f32x4 acc[4][4] = {};
        #pragma unroll
        for (int kt = 0; kt < 8; ++kt) {
            const int g = t * 8 + kt;
            if (g < NG - 1) asm volatile("s_waitcnt vmcnt(2)" ::: "memory");
            else            asm volatile("s_waitcnt vmcnt(0)" ::: "memory");
            __builtin_amdgcn_s_barrier();

            bf16x8 af[4], bfr[4];
            #pragma unroll
            for (int m = 0; m < 4; ++m) {
                const int row = wr * 64 + m * 16 + frow;
                const int p   = (kt * 4 + kgrp) ^ (frow & 7);
                af[m] = *reinterpret_cast<const bf16x8*>(&As[row * 256 + p * 8]);
            }
            const int bbase = (g & 1) * 4096;
            #pragma unroll
            for (int n = 0; n < 4; ++n) {
                const int row = wc * 64 + n * 16 + frow;
                bfr[n] = *reinterpret_cast<const bf16x8*>(&Bs[bbase + row * 32 + bswz]);
            }
            #pragma unroll
            for (int m = 0; m < 4; ++m)
                #pragma unroll
                for (int n = 0; n < 4; ++n)
                    acc[m][n] = __builtin_amdgcn_mfma_f32_16x16x32_bf16(af[m], bfr[n], acc[m][n], 0, 0, 0);

            __builtin_amdgcn_s_barrier();

            if (g + 2 < NG) {
                const int g2 = g + 2;
                const int cb = colBase0 + (g2 >> 3) * 128;
                const int k2 = g2 & 7;
                #pragma unroll
                for (int i = 0; i < 2; ++i) {
                    const int row = wid * 16 + i * 64 + brow_lo;
                    GLOAD_LDS16(B + (size_t)(cb + row) * C + k2 * 32 + bchunk * 8,
                                &Bs[(g2 & 1) * 4096 + wid * 512 + i * 2048 + lane * 8]);
                }
            }
        }

        // ---- epilogue tile t: store raw^T + rowmin
        // C/D map: col cg = colBase + wc*64 + n*16 + frow (s-dim)
        //          row rg = rowBase + wr*64 + m*16 + kgrp*4 + q (r-dim)
        const int colBase = colBase0 + t * 128;
        for (int m = 0; m < 4; ++m) {
            const int rg = rowBase + wr * 64 + m * 16 + kgrp * 4;
            float vq[4] = {1e30f, 1e30f, 1e30f, 1e30f};
            for (int n = 0; n < 4; ++n) {
                us4 pk;
                #pragma unroll
                for (int q = 0; q < 4; ++q) {
                    const float raw = fmaxf(0.5f * (1.0f - acc[m][n][q]), 0.0f);
                    vq[q] = fminf(vq[q], raw);
                    __hip_bfloat16 h = __float2bfloat16(raw);
                    pk[q] = *reinterpret_cast<unsigned short*>(&h);
                }
                const int cg = colBase + wc * 64 + n * 16 + frow;
                *reinterpret_cast<us4*>(Q + (size_t)cg * S + rg) = pk;
            }
            #pragma unroll
            for (int q = 0; q < 4; ++q) {
                float v = vq[q];
                v = fminf(v, __shfl_xor(v, 1, 64));
                v = fminf(v, __shfl_xor(v, 2, 64));
                v = fminf(v, __shfl_xor(v, 4, 64));
                v = fminf(v, __shfl_xor(v, 8, 64));
                if (frow == 0)
                    atomicMin((unsigned int*)&rowmin[rg + q], __float_as_uint(v));
            }
        }
    }
}

// Streaming pass: 64-row strips (full s-range). Sweep 1: rowsum (exact,
// in-block). Sweep 2: cx + per-s max over strip rows -> global atomicMax.
__global__ __launch_bounds__(512) void k_rows(const __hip_bfloat16* __restrict__ Q,
                                              const float* __restrict__ rowmin,
                                              float* __restrict__ colmax) {
    __shared__ float rs[64];   // rowsum, then 1/rowsum
    __shared__ float im[64];   // 1/(rowmin+eps)
    const int t  = threadIdx.x;
    const int r0 = blockIdx.x * 64;
    if (t < 64) {
        im[t] = 1.0f / (rowmin[r0 + t] + 1e-5f);
        rs[t] = 0.f;
    }
    __syncthreads();
    const int roct = (t & 7) * 8;   // this thread's 8-row group
    const int s0   = t >> 3;        // s-stream id (0..63)
    float inv8[8];
    #pragma unroll
    for (int j = 0; j < 8; ++j) inv8[j] = im[roct + j];
    const __hip_bfloat16* base = Q + r0 + roct;

    // ---- sweep 1: rowsum
    float sums[8] = {};
    for (int s = s0; s < S; s += 256) {
        const us8 v0 = *reinterpret_cast<const us8*>(base + (size_t)(s      ) * S);
        const us8 v1 = *reinterpret_cast<const us8*>(base + (size_t)(s +  64) * S);
        const us8 v2 = *reinterpret_cast<const us8*>(base + (size_t)(s + 128) * S);
        const us8 v3 = *reinterpret_cast<const us8*>(base + (size_t)(s + 192) * S);
        #pragma unroll
        for (int j = 0; j < 8; ++j) {
            sums[j] += __expf(2.0f - 2.0f * bf2f(v0[j]) * inv8[j]);
            sums[j] += __expf(2.0f - 2.0f * bf2f(v1[j]) * inv8[j]);
            sums[j] += __expf(2.0f - 2.0f * bf2f(v2[j]) * inv8[j]);
            sums[j] += __expf(2.0f - 2.0f * bf2f(v3[j]) * inv8[j]);
        }
    }
    #pragma unroll
    for (int j = 0; j < 8; ++j) {
        float x = sums[j];
        x += __shfl_xor(x, 8, 64);
        x += __shfl_xor(x, 16, 64);
        x += __shfl_xor(x, 32, 64);
        if ((t & 63) < 8) atomicAdd(&rs[roct + j], x);
    }
    __syncthreads();
    if (t < 64) rs[t] = 1.0f / rs[t];
    __syncthreads();

    // ---- sweep 2: cx + colmax
    float is8[8];
    #pragma unroll
    for (int j = 0; j < 8; ++j) is8[j] = rs[roct + j];
    for (int s = s0; s < S; s += 256) {
        const us8 v0 = *reinterpret_cast<const us8*>(base + (size_t)(s      ) * S);
        const us8 v1 = *reinterpret_cast<const us8*>(base + (size_t)(s +  64) * S);
        const us8 v2 = *reinterpret_cast<const us8*>(base + (size_t)(s + 128) * S);
        const us8 v3 = *reinterpret_cast<const us8*>(base + (size_t)(s + 192) * S);
        float m0 = 0.f, m1 = 0.f, m2 = 0.f, m3 = 0.f;
        #pragma unroll
        for (int j = 0; j < 8; ++j) {
            m0 = fmaxf(m0, __expf(2.0f - 2.0f * bf2f(v0[j]) * inv8[j]) * is8[j]);
            m1 = fmaxf(m1, __expf(2.0f - 2.0f * bf2f(v1[j]) * inv8[j]) * is8[j]);
            m2 = fmaxf(m2, __expf(2.0f - 2.0f * bf2f(v2[j]) * inv8[j]) * is8[j]);
            m3 = fmaxf(m3, __expf(2.0f - 2.0f * bf2f(v3[j]) * inv8[j]) * is8[j]);
        }
        m0 = fmaxf(m0, __shfl_xor(m0, 1, 64)); m1 = fmaxf(m1, __shfl_xor(m1, 1, 64));
        m2 = fmaxf(m2, __shfl_xor(m2, 1, 64)); m3 = fmaxf(m3, __shfl_xor(m3, 1, 64));
        m0 = fmaxf(m0, __shfl_xor(m0, 2, 64)); m1 = fmaxf(m1, __shfl_xor(m1, 2, 64));
        m2 = fmaxf(m2, __shfl_xor(m2, 2, 64)); m3 = fmaxf(m3, __shfl_xor(m3, 2, 64));
        m0 = fmaxf(m0, __shfl_xor(m0, 4, 64)); m1 = fmaxf(m1, __shfl_xor(m1, 4, 64));
        m2 = fmaxf(m2, __shfl_xor(m2, 4, 64)); m3 = fmaxf(m3, __shfl_xor(m3, 4, 64));
        if ((t & 7) == 0) {
            atomicMax((unsigned int*)&colmax[s      ], __float_as_uint(m0));
            atomicMax((unsigned int*)&colmax[s +  64], __float_as_uint(m1));
            atomicMax((unsigned int*)&colmax[s + 128], __float_as_uint(m2));
            atomicMax((unsigned int*)&colmax[s + 192], __float_as_uint(m3));
        }
    }
}

// =====================================================================
// FALLBACK PATH (r3, 3-pass recompute) — used if ws too small for Q
// =====================================================================
template<int PASS>
__global__ __launch_bounds__(256, 2) void k_gemm3(const __hip_bfloat16* __restrict__ A,
                                                  const __hip_bfloat16* __restrict__ B,
                                                  float* __restrict__ rowmin,
                                                  float* __restrict__ rowsum,
                                                  float* __restrict__ colmax) {
    __shared__ alignas(16) __hip_bfloat16 As[128 * 256];
    __shared__ alignas(16) __hip_bfloat16 Bs[2 * 128 * 32];
    const int tid  = threadIdx.x;
    const int lane = tid & 63;
    const int wid  = tid >> 6;
    const int wr   = wid >> 1;
    const int wc   = wid & 1;
    const int rowBase = blockIdx.y * 128;
    const int colBase0 = blockIdx.x * (NCT3 * 128);
    const int frow = lane & 15;
    const int kgrp = lane >> 4;
    {
        const int arow_lo = (lane >> 5);
        const int achunk  = lane & 31;
        #pragma unroll
        for (int j = 0; j < 16; ++j) {
            const int row = wid * 32 + j * 2 + arow_lo;
            const int c   = achunk ^ (row & 7);
            GLOAD_LDS16(A + (size_t)(rowBase + row) * C + c * 8,
                        &As[wid * 8192 + j * 512 + lane * 8]);
        }
    }
    const int brow_lo = lane >> 2;
    const int bchunk  = (lane & 3) ^ ((lane >> 3) & 3);
    #pragma unroll
    for (int g = 0; g < 2; ++g) {
        const int cb = colBase0 + (g >> 3) * 128;
        const int kt = g & 7;
        #pragma unroll
        for (int i = 0; i < 2; ++i) {
            const int row = wid * 16 + i * 64 + brow_lo;
            GLOAD_LDS16(B + (size_t)(cb + row) * C + kt * 32 + bchunk * 8,
                        &Bs[(g & 1) * 4096 + wid * 512 + i * 2048 + lane * 8]);
        }
    }
    const int bswz = (kgrp ^ ((frow >> 1) & 3)) * 8;
    for (int t = 0; t < NCT3; ++t) {
        f32x4 acc[4][4] = {};
        #pragma unroll
        for (int kt = 0; kt < 8; ++kt) {
            const int g = t * 8 + kt;
            if (g < NG3 - 1) asm volatile("s_waitcnt vmcnt(2)" ::: "memory");
            else             asm volatile("s_waitcnt vmcnt(0)" ::: "memory");
            __builtin_amdgcn_s_barrier();
            bf16x8 af[4], bfr[4];
            #pragma unroll
            for (int m = 0; m < 4; ++m) {
                const int row = wr * 64 + m * 16 + frow;
                const int p   = (kt * 4 + kgrp) ^ (frow & 7);
                af[m] = *reinterpret_cast<const bf16x8*>(&As[row * 256 + p * 8]);
            }
            const int bbase = (g & 1) * 4096;
            #pragma unroll
            for (int n = 0; n < 4; ++n) {
                const int row = wc * 64 + n * 16 + frow;
                bfr[n] = *reinterpret_cast<const bf16x8*>(&Bs[bbase + row * 32 + bswz]);
            }
            #pragma unroll
            for (int m = 0; m < 4; ++m)
                #pragma unroll
                for (int n = 0; n < 4; ++n)
                    acc[m][n] = __builtin_amdgcn_mfma_f32_16x16x32_bf16(af[m], bfr[n], acc[m][n], 0, 0, 0);
            __builtin_amdgcn_s_barrier();
            if (g + 2 < NG3) {
                const int g2 = g + 2;
                const int cb = colBase0 + (g2 >> 3) * 128;
                const int k2 = g2 & 7;
                #pragma unroll
                for (int i = 0; i < 2; ++i) {
                    const int row = wid * 16 + i * 64 + brow_lo;
                    GLOAD_LDS16(B + (size_t)(cb + row) * C + k2 * 32 + bchunk * 8,
                                &Bs[(g2 & 1) * 4096 + wid * 512 + i * 2048 + lane * 8]);
                }
            }
        }
        const int colBase = colBase0 + t * 128;
        if (PASS == 1) {
            for (int m = 0; m < 4; ++m)
                for (int q = 0; q < 4; ++q) {
                    float v = 1e30f;
                    for (int n = 0; n < 4; ++n)
                        v = fminf(v, fmaxf(0.5f * (1.0f - acc[m][n][q]), 0.0f));
                    v = fminf(v, __shfl_xor(v, 1, 64));
                    v = fminf(v, __shfl_xor(v, 2, 64));
                    v = fminf(v, __shfl_xor(v, 4, 64));
                    v = fminf(v, __shfl_xor(v, 8, 64));
                    if (frow == 0) {
                        const int rg = rowBase + wr * 64 + m * 16 + kgrp * 4 + q;
                        atomicMin((unsigned int*)&rowmin[rg], __float_as_uint(v));
                    }
                }
        } else if (PASS == 2) {
            for (int m = 0; m < 4; ++m)
                for (int q = 0; q < 4; ++q) {
                    const int rg = rowBase + wr * 64 + m * 16 + kgrp * 4 + q;
                    const float inv = 1.0f / (rowmin[rg] + 1e-5f);
                    float sum = 0.f;
                    for (int n = 0; n < 4; ++n)
                        sum += __expf(2.0f * (1.0f - fmaxf(0.5f * (1.0f - acc[m][n][q]), 0.0f) * inv));
                    sum += __shfl_xor(sum, 1, 64);
                    sum += __shfl_xor(sum, 2, 64);
                    sum += __shfl_xor(sum, 4, 64);
                    sum += __shfl_xor(sum, 8, 64);
                    if (frow == 0) atomicAdd(&rowsum[rg], sum);
                }
        } else {
            float cmax[4] = {0.f, 0.f, 0.f, 0.f};
            for (int m = 0; m < 4; ++m)
                for (int q = 0; q < 4; ++q) {
                    const int rg = rowBase + wr * 64 + m * 16 + kgrp * 4 + q;
                    const float inv = 1.0f / (rowmin[rg] + 1e-5f);
                    const float rsv = 1.0f / rowsum[rg];
                    for (int n = 0; n < 4; ++n) {
                        const float raw = fmaxf(0.5f * (1.0f - acc[m][n][q]), 0.0f);
                        cmax[n] = fmaxf(cmax[n], __expf(2.0f * (1.0f - raw * inv)) * rsv);
                    }
                }
            for (int n = 0; n < 4; ++n) {
                float v = cmax[n];
                v = fmaxf(v, __shfl_xor(v, 16, 64));
                v = fmaxf(v, __shfl_xor(v, 32, 64));
                if (kgrp == 0) {
                    const int cg = colBase + wc * 64 + n * 16 + frow;
                    atomicMax((unsigned int*)&colmax[cg], __float_as_uint(v));
                }
            }
        }
    }
}

// ---------------- final: loss = -log(mean_s colmax[s]) ----------------
__global__ __launch_bounds__(256) void k_final(const float* __restrict__ colmax,
                                               float* __restrict__ out) {
    float s = 0.f;
    for (int i = threadIdx.x; i < S; i += 256) s += colmax[i];
    for (int m = 1; m < 64; m <<= 1) s += __shfl_xor(s, m, 64);
    __shared__ float red[4];
    if ((threadIdx.x & 63) == 0) red[threadIdx.x >> 6] = s;
    __syncthreads();
    if (threadIdx.x == 0)
        out[0] = -logf((red[0] + red[1] + red[2] + red[3]) * (1.0f / S));
}

extern "C" void kernel_launch(void* const* d_in, const int* in_sizes, int n_in,
                              void* d_out, int out_size, void* d_ws, size_t ws_size,
                              hipStream_t stream) {
    const float* img = (const float*)d_in[0];
    const float* gt  = (const float*)d_in[1];

    float* ws     = (float*)d_ws;
    float* meanT  = ws;                  // 256 f
    float* rowmin = ws + 256;            // S f
    float* rowsum = rowmin + S;          // S f (fallback only)
    float* colmax = rowsum + S;          // S f
    __hip_bfloat16* A = (__hip_bfloat16*)(colmax + S);     // off 111,616 B
    __hip_bfloat16* B = A + (size_t)S * C;                 // off 4,830,208 B
    __hip_bfloat16* Q = B + (size_t)S * C;                 // off 9,548,800 B
    const size_t NEED = 9548800ull + (size_t)S * S * 2ull; // ~179.4 MB
    float* out = (float*)d_out;

    k_mean<<<C, 256, 0, stream>>>(gt, meanT);
    k_norm<<<(S * 4) / 256, 256, 0, stream>>>(img, gt, meanT, A, B);
    k_init<<<(S + 255) / 256, 256, 0, stream>>>(rowmin, rowsum, colmax);

    if (ws_size >= NEED) {
        k_gemm_store<<<648, 256, 0, stream>>>(A, B, rowmin, Q);
        k_rows<<<S / 64, 512, 0, stream>>>(Q, rowmin, colmax);
    } else {
        dim3 grid(72 / NCT3, 72);
        k_gemm3<1><<<grid, 256, 0, stream>>>(A, B, rowmin, rowsum, colmax);
        k_gemm3<2><<<grid, 256, 0, stream>>>(A, B, rowmin, rowsum, colmax);
        k_gemm3<3><<<grid, 256, 0, stream>>>(A, B, rowmin, rowsum, colmax);
    }

    k_final<<<1, 256, 0, stream>>>(colmax, out);
}